// Round 11
// baseline (260.261 us; speedup 1.0000x reference)
//
#include <hip/hip_runtime.h>
#include <hip/hip_bf16.h>
#include <cfloat>

#define B_   2
#define NQ_  1024
#define NK_  2048
#define H_   16
#define HD_  64
#define VPAD 2176      // vpT row stride in bf16 elements
#define GPAD 2112      // dmask row stride in bf16 elements

typedef float  floatx4 __attribute__((ext_vector_type(4)));
typedef __bf16 bf16x8  __attribute__((ext_vector_type(8)));
typedef __bf16 bf16x4  __attribute__((ext_vector_type(4)));

static __device__ __forceinline__ floatx4 mfma16(bf16x8 a, bf16x8 b, floatx4 c) {
    return __builtin_amdgcn_mfma_f32_16x16x32_bf16(a, b, c, 0, 0, 0);
}

// global -> LDS direct copy, 16B per lane. lbase wave-uniform.
static __device__ __forceinline__ void gl_lds(const __bf16* g, __bf16* lbase,
                                              int lane) {
#if __has_builtin(__builtin_amdgcn_global_load_lds)
    __builtin_amdgcn_global_load_lds(
        (const __attribute__((address_space(1))) void*)g,
        (__attribute__((address_space(3))) void*)lbase, 16, 0, 0);
#else
    *(bf16x8*)(lbase + lane * 8) = *(const bf16x8*)g;
#endif
}

// ---------------------------------------------------------------------------
// Kernel 0 (R11 slim): weight f32->bf16 conversion (blocks 0..511) +
// per-batch masked distance sum AND masked-d bf16 emit (blocks 512..1535).
// q/k/v conversion is now FUSED into proj_kernel's staging (saves the
// 88 MB cvt round-trip; proj reads f32 directly).
// dmask[b][q][k] = masked ? d : 3e38 (sentinel; attn's c<0 turns it into 0)
// ---------------------------------------------------------------------------
struct CvtArgs {
    const float* src[7];
    __bf16*      dst[7];
};

__global__ __launch_bounds__(256) void cvt_mean_kernel(
    CvtArgs a, const float* __restrict__ dist, const int* __restrict__ amask,
    const int* __restrict__ kpmk, float* __restrict__ msum,
    __bf16* __restrict__ dmask)
{
    if (blockIdx.x >= 512) {
        const int mb = blockIdx.x - 512;       // 0..1023
        const int b  = mb >> 9;                // 0..1
        const float* d  = dist  + (size_t)b * NQ_ * NK_;
        const int*   am = amask + (size_t)b * NQ_ * NK_;
        const int*   km = kpmk  + b * NK_;
        __bf16*      dm = dmask + (size_t)b * NQ_ * GPAD;
        const int base = (mb & 511) * 256 + threadIdx.x;   // 0..131071
        float s = 0.f;
        #pragma unroll
        for (int j = 0; j < 4; j++) {
            const int i   = base + j * 131072;
            const int idx = i * 4;
            const int kk  = idx & (NK_ - 1);
            const int q   = i >> 9;
            float4 dv = *(const float4*)(d + idx);
            int4   mv = *(const int4*)(am + idx);
            int4   kv = *(const int4*)(km + kk);
            bf16x4 o;
            if (mv.x && kv.x) { s += dv.x; o[0] = (__bf16)dv.x; } else o[0] = (__bf16)3e38f;
            if (mv.y && kv.y) { s += dv.y; o[1] = (__bf16)dv.y; } else o[1] = (__bf16)3e38f;
            if (mv.z && kv.z) { s += dv.z; o[2] = (__bf16)dv.z; } else o[2] = (__bf16)3e38f;
            if (mv.w && kv.w) { s += dv.w; o[3] = (__bf16)dv.w; } else o[3] = (__bf16)3e38f;
            *(bf16x4*)&dm[(size_t)q * GPAD + kk] = o;
        }
        #pragma unroll
        for (int off = 32; off >= 1; off >>= 1) s += __shfl_down(s, off);
        __shared__ float wsum[4];
        if ((threadIdx.x & 63) == 0) wsum[threadIdx.x >> 6] = s;
        __syncthreads();
        if (threadIdx.x == 0)
            atomicAdd(&msum[b], wsum[0] + wsum[1] + wsum[2] + wsum[3]);
        return;
    }
    // weight-cvt part: 4 tensors x 131072 groups of 8 = 524288 groups,
    // 512 blocks x 256 threads x 4 groups.
    #pragma unroll
    for (int j = 0; j < 4; j++) {
        size_t r = (size_t)blockIdx.x * 1024 + j * 256 + threadIdx.x;
        const int s = 3 + (int)(r >> 17);     // 3..6 (Wq,Wk,Wv,Wo)
        r &= 131071;
        const float* sp = a.src[s] + r * 8;
        float4 f0 = *(const float4*)sp;
        float4 f1 = *(const float4*)(sp + 4);
        bf16x8 o;
        o[0] = (__bf16)f0.x; o[1] = (__bf16)f0.y; o[2] = (__bf16)f0.z; o[3] = (__bf16)f0.w;
        o[4] = (__bf16)f1.x; o[5] = (__bf16)f1.y; o[6] = (__bf16)f1.z; o[7] = (__bf16)f1.w;
        *(bf16x8*)(a.dst[s] + r * 8) = o;
    }
}

// ---------------------------------------------------------------------------
// R11 GEMM core with FUSED f32->bf16 conversion on one operand.
// AF32=true : A = Fsrc (f32, reg-staged + converted), B = Bsrc (bf16 gl_lds)
// AF32=false: A = Bsrc (bf16 gl_lds),                B = Fsrc (f32 staged)
// f32 staging: 2 threads/row (row=t>>1, 16-col half each); loads for step
// k+1 issue right after barrier-2 -> full MFMA phase of slack before the
// next barrier's vmcnt drain (R5-proven placement). LDS layout identical to
// the gl_lds path, so the MFMA phase is unchanged.
// ---------------------------------------------------------------------------
template <bool AF32, typename EPI>
static __device__ __forceinline__ void gemm128c_core(
    const float* __restrict__ Fsrc, const __bf16* __restrict__ Bsrc,
    int m0, int n0, __bf16* As, __bf16* Bs, EPI epi)
{
    const int t    = threadIdx.x;
    const int w    = t >> 6, lane = t & 63;
    const int lrow = lane & 15, quad = lane >> 4;
    const int lr   = lane >> 2, lc = lane & 3;
    const int frow = t >> 1, fc16 = (t & 1) * 16;   // f32 staging map

    floatx4 acc[4][4];
    #pragma unroll
    for (int mi = 0; mi < 4; mi++)
        #pragma unroll
        for (int ni = 0; ni < 4; ni++) acc[mi][ni] = floatx4{0.f, 0.f, 0.f, 0.f};

    const float*  gf  = Fsrc + (size_t)((AF32 ? m0 : n0) + frow) * 1024 + fc16;
    const __bf16* gbb = Bsrc + (size_t)((AF32 ? n0 : m0) + w * 32 + lr) * 1024 + lc * 8;
    __bf16* Fls = AF32 ? As : Bs;    // LDS tile fed by the f32 operand
    __bf16* Bls = AF32 ? Bs : As;    // LDS tile fed by gl_lds

    float4 fr[2][4];
    auto issueF = [&](int k0) {
        #pragma unroll
        for (int h = 0; h < 2; h++)
            #pragma unroll
            for (int j = 0; j < 4; j++)
                fr[h][j] = *(const float4*)(gf + k0 + h * 32 + j * 4);
    };
    auto writeF = [&]() {
        #pragma unroll
        for (int h = 0; h < 2; h++) {
            bf16x8 o0, o1;
            o0[0] = (__bf16)fr[h][0].x; o0[1] = (__bf16)fr[h][0].y;
            o0[2] = (__bf16)fr[h][0].z; o0[3] = (__bf16)fr[h][0].w;
            o0[4] = (__bf16)fr[h][1].x; o0[5] = (__bf16)fr[h][1].y;
            o0[6] = (__bf16)fr[h][1].z; o0[7] = (__bf16)fr[h][1].w;
            o1[0] = (__bf16)fr[h][2].x; o1[1] = (__bf16)fr[h][2].y;
            o1[2] = (__bf16)fr[h][2].z; o1[3] = (__bf16)fr[h][2].w;
            o1[4] = (__bf16)fr[h][3].x; o1[5] = (__bf16)fr[h][3].y;
            o1[6] = (__bf16)fr[h][3].z; o1[7] = (__bf16)fr[h][3].w;
            *(bf16x8*)&Fls[h * 4096 + frow * 32 + fc16]     = o0;
            *(bf16x8*)&Fls[h * 4096 + frow * 32 + fc16 + 8] = o1;
        }
    };

    issueF(0);
    for (int k0 = 0; k0 < 1024; k0 += 64) {
        __syncthreads();                // barrier-1: prior MFMA reads done
        writeF();                       // fr ready (drained by barrier-1)
        #pragma unroll
        for (int h = 0; h < 2; h++) {
            gl_lds(gbb + k0 + h * 32,             &Bls[h * 4096 + (w * 32) * 32],      lane);
            gl_lds(gbb + k0 + h * 32 + 16 * 1024, &Bls[h * 4096 + (w * 32 + 16) * 32], lane);
        }
        __syncthreads();                // barrier-2: staging visible
        if (k0 + 64 < 1024) issueF(k0 + 64);   // full MFMA phase of slack

        #pragma unroll
        for (int h = 0; h < 2; h++) {
            bf16x8 af[4], bfr[4];
            #pragma unroll
            for (int mi = 0; mi < 4; mi++)
                af[mi] = *(const bf16x8*)
                    &As[h * 4096 + ((w & 1) * 64 + mi * 16 + lrow) * 32 + quad * 8];
            #pragma unroll
            for (int ni = 0; ni < 4; ni++)
                bfr[ni] = *(const bf16x8*)
                    &Bs[h * 4096 + ((w >> 1) * 64 + ni * 16 + lrow) * 32 + quad * 8];
            #pragma unroll
            for (int mi = 0; mi < 4; mi++)
                #pragma unroll
                for (int ni = 0; ni < 4; ni++)
                    acc[mi][ni] = mfma16(af[mi], bfr[ni], acc[mi][ni]);
        }
    }

    #pragma unroll
    for (int mi = 0; mi < 4; mi++)
        #pragma unroll
        for (int ni = 0; ni < 4; ni++)
            #pragma unroll
            for (int r = 0; r < 4; r++) {
                const int m = m0 + (w & 1) * 64 + mi * 16 + quad * 4 + r;
                const int n = n0 + (w >> 1) * 64 + ni * 16 + lrow;
                epi(m, n, acc[mi][ni][r]);
            }
}

// Fused projection kernel: z = 0 -> qp, 1 -> kp, 2 -> vpT (operand-swapped).
// R11: reads q/k/v directly in f32 (conversion fused into staging).
__global__ __launch_bounds__(256) void proj_kernel(
    const float* __restrict__ qf, const float* __restrict__ kf,
    const float* __restrict__ vf, const __bf16* __restrict__ wqb,
    const __bf16* __restrict__ wkb, const __bf16* __restrict__ wvb,
    __bf16* __restrict__ qp, __bf16* __restrict__ kp,
    __bf16* __restrict__ vpT)
{
    __shared__ alignas(16) __bf16 As[2 * 128 * 32];
    __shared__ alignas(16) __bf16 Bs[2 * 128 * 32];
    const int z = blockIdx.z;
    if (z == 0) {
        if ((int)blockIdx.x >= 16) return;
        gemm128c_core<true>(qf, wqb, blockIdx.x * 128, blockIdx.y * 128,
                            As, Bs, [&](int m, int n, float v) {
            const int b = m >> 10, q = m & 1023;
            const int h = n >> 6,  d = n & 63;
            qp[(((size_t)(b * 16 + h) * NQ_ + q) << 6) + d] = (__bf16)v;
        });
    } else if (z == 1) {
        gemm128c_core<true>(kf, wkb, blockIdx.x * 128, blockIdx.y * 128,
                            As, Bs, [&](int m, int n, float v) {
            const int b = m >> 11, key = m & 2047;
            const int h = n >> 6,  d = n & 63;
            kp[(((size_t)(b * 16 + h) * NK_ + key) << 6) + d] = (__bf16)v;
        });
    } else {
        // swapped: A = Wv (bf16, gl_lds), B = V (f32, staged+converted)
        gemm128c_core<false>(vf, wvb, blockIdx.y * 128, blockIdx.x * 128,
                             As, Bs, [&](int m, int n, float v) {
            const int h = m >> 6,  d = m & 63;
            const int b = n >> 11, key = n & 2047;
            vpT[((size_t)(b * 16 + h) * HD_ + d) * VPAD + key] = (__bf16)v;
        });
    }
}

// ---------------------------------------------------------------------------
// Output projection (R10 structure): 64x128 tile, 512 threads (2x4 waves),
// grid (32,8) = 256 blocks; 8 waves/block = 2 waves/SIMD.
// ---------------------------------------------------------------------------
__global__ __launch_bounds__(512) void oproj_kernel(
    const __bf16* __restrict__ A, const __bf16* __restrict__ W,
    float* __restrict__ Cout)
{
    __shared__ alignas(16) __bf16 As[2][64 * 32];
    __shared__ alignas(16) __bf16 Bs[2][128 * 32];
    const int t    = threadIdx.x;
    const int w    = t >> 6, lane = t & 63;
    const int lrow = lane & 15, quad = lane >> 4;
    const int lr   = lane >> 2, lc = lane & 3;
    const int m0 = blockIdx.x * 64, n0 = blockIdx.y * 128;
    const int wm = w & 1, wn = w >> 1;   // 2 x 4 wave grid, 32x32 out each

    floatx4 acc[2][2];
    #pragma unroll
    for (int mi = 0; mi < 2; mi++)
        #pragma unroll
        for (int ni = 0; ni < 2; ni++) acc[mi][ni] = floatx4{0.f, 0.f, 0.f, 0.f};

    const __bf16* ga = A + (size_t)(m0 + (w & 3) * 16 + lr) * 1024 + lc * 8;
    const __bf16* gb = W + (size_t)(n0 + w * 16 + lr) * 1024 + lc * 8;

    for (int k0 = 0; k0 < 1024; k0 += 64) {
        __syncthreads();
        #pragma unroll
        for (int h = 0; h < 2; h++) {
            if (w < 4)
                gl_lds(ga + k0 + h * 32, &As[h][(w * 16) * 32], lane);
            gl_lds(gb + k0 + h * 32, &Bs[h][(w * 16) * 32], lane);
        }
        __syncthreads();

        #pragma unroll
        for (int h = 0; h < 2; h++) {
            bf16x8 af[2], bfr[2];
            #pragma unroll
            for (int mi = 0; mi < 2; mi++)
                af[mi] = *(const bf16x8*)
                    &As[h][(wm * 32 + mi * 16 + lrow) * 32 + quad * 8];
            #pragma unroll
            for (int ni = 0; ni < 2; ni++)
                bfr[ni] = *(const bf16x8*)
                    &Bs[h][(wn * 32 + ni * 16 + lrow) * 32 + quad * 8];
            #pragma unroll
            for (int mi = 0; mi < 2; mi++)
                #pragma unroll
                for (int ni = 0; ni < 2; ni++)
                    acc[mi][ni] = mfma16(af[mi], bfr[ni], acc[mi][ni]);
        }
    }

    #pragma unroll
    for (int mi = 0; mi < 2; mi++)
        #pragma unroll
        for (int ni = 0; ni < 2; ni++)
            #pragma unroll
            for (int r = 0; r < 4; r++) {
                const int m = m0 + wm * 32 + mi * 16 + quad * 4 + r;
                const int n = n0 + wn * 32 + ni * 16 + lrow;
                Cout[(size_t)m * 1024 + n] = acc[mi][ni][r];
            }
}

// ---------------------------------------------------------------------------
// Fused attention, split-K (2 halves), 32 q-rows/wave — EXACT R5 kernel
// (best measured attn: 47.7-49.7 us). kf/vf fragment reads SHARED across the
// two Q row-groups (DS/MFMA = 1.0); 2 barriers/tile; Vt[2] double-buffer;
// prefetch loads issued right after barrier-2 (full tile before next drain).
// Grid 512 = 8 qt x 32 bh x 2 k-halves; 2 blocks/CU resident, single round.
// ---------------------------------------------------------------------------
__global__ __launch_bounds__(256, 2) void attn_kernel(
    const __bf16* __restrict__ qp, const __bf16* __restrict__ kp,
    const __bf16* __restrict__ vpT, const __bf16* __restrict__ dmask,
    const float* __restrict__ msum, const float* __restrict__ galpha,
    float* __restrict__ Opart, float* __restrict__ Gpart)
{
    __shared__ __bf16 Ks[64 * 72];
    __shared__ __bf16 Vt[2][64 * 72];
    __shared__ __bf16 Ps[4][32 * 72];
    const int t    = threadIdx.x;
    const int w    = t >> 6, lane = t & 63;
    const int lrow = lane & 15, quad = lane >> 4;
    const int bid  = ((blockIdx.x & 7) << 6) | (blockIdx.x >> 3); // XCD swizzle
    const int qt   = bid & 7;             // 0..7   (128-row q tiles)
    const int bh   = (bid >> 3) & 31;     // 0..31
    const int z    = bid >> 8;            // 0..1 k-half
    const int b    = bh >> 4, h = bh & 15;
    const int q0   = qt * 128 + w * 32;   // wave's 32-row base
    const int kb0  = z * (NK_ / 2);
    const int NT   = NK_ / 128;           // 16 tiles of 64 keys

    const float mean  = fmaxf(msum[b] / ((float)(NQ_ * NK_) + 1e-6f), 1e-6f);
    const float alpha = log1pf(__expf(galpha[0]));
    const float cg    = -alpha / mean;    // strictly negative

    // Q fragments for both 16-row groups
    bf16x8 qf0[2], qf1[2];
    #pragma unroll
    for (int g = 0; g < 2; g++) {
        const __bf16* qb = qp + ((size_t)bh * NQ_ + q0 + g * 16 + lrow) * HD_
                         + quad * 8;
        qf0[g] = *(const bf16x8*)qb;
        qf1[g] = *(const bf16x8*)(qb + 32);
    }

    const int srow0 = t >> 3,        sc0 = t & 7;
    const int srow1 = 32 + (t >> 3), sc1 = t & 7;
    const int so0 = srow0 * 72 + sc0 * 8;
    const int so1 = srow1 * 72 + sc1 * 8;
    const __bf16* Kg = kp  + ((size_t)bh * NK_ + kb0) * HD_;
    const __bf16* Vg = vpT + (size_t)bh * HD_ * VPAD + kb0;
    const __bf16* grow0 = dmask + ((size_t)b * NQ_ + q0 + lrow) * GPAD + kb0;
    const __bf16* grow1 = grow0 + (size_t)16 * GPAD;

    float G[2] = {0.f, 0.f};
    floatx4 O[2][4];
    #pragma unroll
    for (int g = 0; g < 2; g++)
        #pragma unroll
        for (int nb = 0; nb < 4; nb++) O[g][nb] = floatx4{0.f, 0.f, 0.f, 0.f};

    bf16x8 kr0, kr1, vr0, vr1;
    bf16x4 gr[2][4];
    auto loadt = [&](int kb) {
        kr0 = *(const bf16x8*)(Kg + (size_t)(kb + srow0) * HD_ + sc0 * 8);
        kr1 = *(const bf16x8*)(Kg + (size_t)(kb + srow1) * HD_ + sc1 * 8);
        vr0 = *(const bf16x8*)(Vg + (size_t)srow0 * VPAD + kb + sc0 * 8);
        vr1 = *(const bf16x8*)(Vg + (size_t)srow1 * VPAD + kb + sc1 * 8);
        #pragma unroll
        for (int c = 0; c < 4; c++) {
            gr[0][c] = *(const bf16x4*)(grow0 + kb + c * 16 + quad * 4);
            gr[1][c] = *(const bf16x4*)(grow1 + kb + c * 16 + quad * 4);
        }
    };
    loadt(0);

    for (int ib = 0; ib < NT; ib++) {
        const int kb  = ib * 64;
        const int cur = ib & 1;

        __syncthreads();                  // prior Ks / Vt[cur] reads complete
        *(bf16x8*)&Ks[so0]      = kr0;
        *(bf16x8*)&Ks[so1]      = kr1;
        *(bf16x8*)&Vt[cur][so0] = vr0;
        *(bf16x8*)&Vt[cur][so1] = vr1;
        __syncthreads();                  // staging visible

        bf16x4 gcur[2][4];
        #pragma unroll
        for (int g = 0; g < 2; g++)
            #pragma unroll
            for (int c = 0; c < 4; c++) gcur[g][c] = gr[g][c];
        if (ib + 1 < NT) loadt(kb + 64);  // full tile before next drain

        __builtin_amdgcn_s_setprio(1);
        // --- QK(i): kf shared across both Q groups ---
        floatx4 s4[2][4];
        #pragma unroll
        for (int c = 0; c < 4; c++) {
            bf16x8 kf0 = *(const bf16x8*)&Ks[(c * 16 + lrow) * 72 + quad * 8];
            bf16x8 kf1 = *(const bf16x8*)&Ks[(c * 16 + lrow) * 72 + 32 + quad * 8];
            #pragma unroll
            for (int g = 0; g < 2; g++) {
                floatx4 a = floatx4{0.f, 0.f, 0.f, 0.f};
                a = mfma16(kf0, qf0[g], a);
                a = mfma16(kf1, qf1[g], a);
                s4[g][c] = a;
            }
        }

        // --- PV(i-1): vf shared across both P groups ---
        if (ib > 0) {
            const int prv = cur ^ 1;
            bf16x8 pf0[2], pf1[2];
            #pragma unroll
            for (int g = 0; g < 2; g++) {
                pf0[g] = *(const bf16x8*)&Ps[w][(g * 16 + lrow) * 72 + quad * 8];
                pf1[g] = *(const bf16x8*)&Ps[w][(g * 16 + lrow) * 72 + 32 + quad * 8];
            }
            #pragma unroll
            for (int nb = 0; nb < 4; nb++) {
                bf16x8 vf0 = *(const bf16x8*)
                    &Vt[prv][(nb * 16 + lrow) * 72 + quad * 8];
                bf16x8 vf1 = *(const bf16x8*)
                    &Vt[prv][(nb * 16 + lrow) * 72 + 32 + quad * 8];
                #pragma unroll
                for (int g = 0; g < 2; g++) {
                    O[g][nb] = mfma16(pf0[g], vf0, O[g][nb]);
                    O[g][nb] = mfma16(pf1[g], vf1, O[g][nb]);
                }
            }
        }
        __builtin_amdgcn_s_setprio(0);

        // --- exp(i): eg = exp(s/8 + c*d) -> Ps (single-buffered; PV-read ->
        // exp-write are same-wave DS ops, retired in order) ---
        #pragma unroll
        for (int g = 0; g < 2; g++)
            #pragma unroll
            for (int c = 0; c < 4; c++) {
                const float e0 = __expf(fmaf(s4[g][c][0], 0.125f, cg * (float)gcur[g][c][0]));
                const float e1 = __expf(fmaf(s4[g][c][1], 0.125f, cg * (float)gcur[g][c][1]));
                const float e2 = __expf(fmaf(s4[g][c][2], 0.125f, cg * (float)gcur[g][c][2]));
                const float e3 = __expf(fmaf(s4[g][c][3], 0.125f, cg * (float)gcur[g][c][3]));
                G[g] += (e0 + e1) + (e2 + e3);
                bf16x4 pk;
                pk[0] = (__bf16)e0; pk[1] = (__bf16)e1;
                pk[2] = (__bf16)e2; pk[3] = (__bf16)e3;
                *(bf16x4*)&Ps[w][(g * 16 + lrow) * 72 + c * 16 + quad * 4] = pk;
            }
    }

    // --- final PV(NT-1) ---
    {
        const int prv = (NT - 1) & 1;
        bf16x8 pf0[2], pf1[2];
        #pragma unroll
        for (int g = 0; g < 2; g++) {
            pf0[g] = *(const bf16x8*)&Ps[w][(g * 16 + lrow) * 72 + quad * 8];
            pf1[g] = *(const bf16x8*)&Ps[w][(g * 16 + lrow) * 72 + 32 + quad * 8];
        }
        #pragma unroll
        for (int nb = 0; nb < 4; nb++) {
            bf16x8 vf0 = *(const bf16x8*)&Vt[prv][(nb * 16 + lrow) * 72 + quad * 8];
            bf16x8 vf1 = *(const bf16x8*)&Vt[prv][(nb * 16 + lrow) * 72 + 32 + quad * 8];
            #pragma unroll
            for (int g = 0; g < 2; g++) {
                O[g][nb] = mfma16(pf0[g], vf0, O[g][nb]);
                O[g][nb] = mfma16(pf1[g], vf1, O[g][nb]);
            }
        }
    }

    // Partial G per group: reduce across quads; raw f32 partials out.
    #pragma unroll
    for (int g = 0; g < 2; g++) {
        G[g] += __shfl_xor(G[g], 16);
        G[g] += __shfl_xor(G[g], 32);
    }

    #pragma unroll
    for (int g = 0; g < 2; g++) {
        float* Op = Opart + (size_t)z * (B_ * NQ_ * 1024)
                          + ((size_t)b * NQ_ + q0 + g * 16) * 1024 + h * HD_;
        #pragma unroll
        for (int r = 0; r < 4; r++) {
            const int qr = quad * 4 + r;
            #pragma unroll
            for (int nb = 0; nb < 4; nb++)
                Op[(size_t)qr * 1024 + nb * 16 + lrow] = O[g][nb][r];
        }
        if (lane < 16)
            Gpart[(size_t)z * (32 * 1024) + bh * 1024 + q0 + g * 16 + lane] = G[g];
    }
}

// Combine the two k-half partials: attnout = (O0+O1) * kpm_q / (G0+G1).
// 2048 x 1024 elements, 4 cols/thread -> 2048 blocks. ~21 MB traffic.
__global__ __launch_bounds__(256) void combine_kernel(
    const float* __restrict__ Opart, const float* __restrict__ Gpart,
    const int* __restrict__ kpmq, __bf16* __restrict__ attnout)
{
    const int idx = blockIdx.x * 256 + threadIdx.x;   // 0..524287
    const int m   = idx >> 8;            // row 0..2047
    const int c4  = (idx & 255) * 4;     // col 0..1020
    const int b   = m >> 10, q = m & 1023;
    const int h   = c4 >> 6;
    const float g = Gpart[(b * 16 + h) * 1024 + q]
                  + Gpart[32 * 1024 + (b * 16 + h) * 1024 + q];
    const float f = kpmq[b * NQ_ + q] ? 1.f / (g + 1e-30f) : 0.f;
    const float4 o0 = *(const float4*)(Opart + (size_t)m * 1024 + c4);
    const float4 o1 = *(const float4*)(Opart + (size_t)(B_ * NQ_) * 1024
                                              + (size_t)m * 1024 + c4);
    bf16x4 r;
    r[0] = (__bf16)((o0.x + o1.x) * f);
    r[1] = (__bf16)((o0.y + o1.y) * f);
    r[2] = (__bf16)((o0.z + o1.z) * f);
    r[3] = (__bf16)((o0.w + o1.w) * f);
    *(bf16x4*)&attnout[(size_t)m * 1024 + c4] = r;
}

// ---------------------------------------------------------------------------
extern "C" void kernel_launch(void* const* d_in, const int* in_sizes, int n_in,
                              void* d_out, int out_size, void* d_ws,
                              size_t ws_size, hipStream_t stream)
{
    const float* q      = (const float*)d_in[0];
    const float* k      = (const float*)d_in[1];
    const float* v      = (const float*)d_in[2];
    const float* dist   = (const float*)d_in[3];
    const int*   amask  = (const int*)d_in[4];
    const int*   kpmq   = (const int*)d_in[5];
    const int*   kpmk   = (const int*)d_in[6];
    const float* Wq     = (const float*)d_in[7];
    const float* Wk     = (const float*)d_in[8];
    const float* Wv     = (const float*)d_in[9];
    const float* Wo     = (const float*)d_in[10];
    const float* galpha = (const float*)d_in[11];

    char* p = (char*)d_ws;
    float*  msum = (float*)p;                 p += 256;
    __bf16* qb   = (__bf16*)p;                p += (size_t)2097152 * 2;
    __bf16* kb   = (__bf16*)p;                p += (size_t)4194304 * 2;
    __bf16* vb   = (__bf16*)p;                p += (size_t)4194304 * 2;
    __bf16* wqb  = (__bf16*)p;                p += (size_t)1048576 * 2;
    __bf16* wkb  = (__bf16*)p;                p += (size_t)1048576 * 2;
    __bf16* wvb  = (__bf16*)p;                p += (size_t)1048576 * 2;
    __bf16* wob  = (__bf16*)p;                p += (size_t)1048576 * 2;
    __bf16* qp   = (__bf16*)p;                p += (size_t)2097152 * 2;
    __bf16* kpb  = (__bf16*)p;                p += (size_t)4194304 * 2;
    __bf16* vpT  = (__bf16*)p;                p += (size_t)32 * 64 * VPAD * 2;
    __bf16* dmask = (__bf16*)p;               p += (size_t)2048 * GPAD * 2;
    __bf16* attnout = (__bf16*)p;             p += (size_t)2097152 * 2;

    // Split-K partial buffers OVERLAY the (now-unused-for-staging) qb/kb/vb
    // buffers: Opart (16 MiB) on kb+vb, Gpart (256 KiB) on qb.
    float* Opart = (float*)kb;
    float* Gpart = (float*)qb;

    CvtArgs ca;
    ca.src[0] = nullptr; ca.src[1] = nullptr; ca.src[2] = nullptr;
    ca.src[3] = Wq; ca.src[4] = Wk; ca.src[5] = Wv; ca.src[6] = Wo;
    ca.dst[0] = nullptr; ca.dst[1] = nullptr; ca.dst[2] = nullptr;
    ca.dst[3] = wqb; ca.dst[4] = wkb; ca.dst[5] = wvb; ca.dst[6] = wob;

    hipMemsetAsync(msum, 0, 256, stream);
    cvt_mean_kernel<<<1536, 256, 0, stream>>>(ca, dist, amask, kpmk, msum,
                                              dmask);
    proj_kernel<<<dim3(32, 8, 3), 256, 0, stream>>>(q, k, v, wqb, wkb, wvb,
                                                    qp, kpb, vpT);
    attn_kernel<<<512, 256, 0, stream>>>(qp, kpb, vpT, dmask,
                                         msum, galpha, Opart, Gpart);
    combine_kernel<<<2048, 256, 0, stream>>>(Opart, Gpart, kpmq, attnout);
    oproj_kernel<<<dim3(32, 8), 512, 0, stream>>>(attnout, wob, (float*)d_out);
}

// Round 12
// 248.807 us; speedup vs baseline: 1.0460x; 1.0460x over previous
//
#include <hip/hip_runtime.h>
#include <hip/hip_bf16.h>
#include <cfloat>

#define B_   2
#define NQ_  1024
#define NK_  2048
#define H_   16
#define HD_  64
#define VPAD 2176      // vpT row stride in bf16 elements
#define GPAD 2112      // dmask row stride in bf16 elements

typedef float  floatx4 __attribute__((ext_vector_type(4)));
typedef __bf16 bf16x8  __attribute__((ext_vector_type(8)));
typedef __bf16 bf16x4  __attribute__((ext_vector_type(4)));

static __device__ __forceinline__ floatx4 mfma16(bf16x8 a, bf16x8 b, floatx4 c) {
    return __builtin_amdgcn_mfma_f32_16x16x32_bf16(a, b, c, 0, 0, 0);
}

// global -> LDS direct copy, 16B per lane. lbase wave-uniform.
static __device__ __forceinline__ void gl_lds(const __bf16* g, __bf16* lbase,
                                              int lane) {
#if __has_builtin(__builtin_amdgcn_global_load_lds)
    __builtin_amdgcn_global_load_lds(
        (const __attribute__((address_space(1))) void*)g,
        (__attribute__((address_space(3))) void*)lbase, 16, 0, 0);
#else
    *(bf16x8*)(lbase + lane * 8) = *(const bf16x8*)g;
#endif
}

// ---------------------------------------------------------------------------
// Kernel 0 (restored R5 full form): fused f32->bf16 conversion (blocks
// 0..1791, q/k/v + weights) + per-batch masked distance sum AND masked-d
// bf16 emit (blocks 1792..2815).
// dmask[b][q][k] = masked ? d : 3e38 (sentinel; attn's c<0 turns it into 0)
// ---------------------------------------------------------------------------
struct CvtArgs {
    const float* src[7];
    __bf16*      dst[7];
};

__global__ __launch_bounds__(256) void cvt_mean_kernel(
    CvtArgs a, const float* __restrict__ dist, const int* __restrict__ amask,
    const int* __restrict__ kpmk, float* __restrict__ msum,
    __bf16* __restrict__ dmask)
{
    if (blockIdx.x >= 1792) {
        const int mb = blockIdx.x - 1792;      // 0..1023
        const int b  = mb >> 9;                // 0..1
        const float* d  = dist  + (size_t)b * NQ_ * NK_;
        const int*   am = amask + (size_t)b * NQ_ * NK_;
        const int*   km = kpmk  + b * NK_;
        __bf16*      dm = dmask + (size_t)b * NQ_ * GPAD;
        const int base = (mb & 511) * 256 + threadIdx.x;   // 0..131071
        float s = 0.f;
        #pragma unroll
        for (int j = 0; j < 4; j++) {
            const int i   = base + j * 131072;
            const int idx = i * 4;
            const int kk  = idx & (NK_ - 1);
            const int q   = i >> 9;
            float4 dv = *(const float4*)(d + idx);
            int4   mv = *(const int4*)(am + idx);
            int4   kv = *(const int4*)(km + kk);
            bf16x4 o;
            if (mv.x && kv.x) { s += dv.x; o[0] = (__bf16)dv.x; } else o[0] = (__bf16)3e38f;
            if (mv.y && kv.y) { s += dv.y; o[1] = (__bf16)dv.y; } else o[1] = (__bf16)3e38f;
            if (mv.z && kv.z) { s += dv.z; o[2] = (__bf16)dv.z; } else o[2] = (__bf16)3e38f;
            if (mv.w && kv.w) { s += dv.w; o[3] = (__bf16)dv.w; } else o[3] = (__bf16)3e38f;
            *(bf16x4*)&dm[(size_t)q * GPAD + kk] = o;
        }
        #pragma unroll
        for (int off = 32; off >= 1; off >>= 1) s += __shfl_down(s, off);
        __shared__ float wsum[4];
        if ((threadIdx.x & 63) == 0) wsum[threadIdx.x >> 6] = s;
        __syncthreads();
        if (threadIdx.x == 0)
            atomicAdd(&msum[b], wsum[0] + wsum[1] + wsum[2] + wsum[3]);
        return;
    }
    // cvt part: 1792 blocks x 256 threads x 4 groups = 1835008 groups of 8
    #pragma unroll
    for (int j = 0; j < 4; j++) {
        size_t r = (size_t)blockIdx.x * 1024 + j * 256 + threadIdx.x;
        int s;
        if (r < 262144)                  { s = 0; }
        else if ((r -= 262144) < 524288) { s = 1; }
        else if ((r -= 524288) < 524288) { s = 2; }
        else { r -= 524288; s = 3 + (int)(r >> 17); r &= 131071; }
        const float* sp = a.src[s] + r * 8;
        float4 f0 = *(const float4*)sp;
        float4 f1 = *(const float4*)(sp + 4);
        bf16x8 o;
        o[0] = (__bf16)f0.x; o[1] = (__bf16)f0.y; o[2] = (__bf16)f0.z; o[3] = (__bf16)f0.w;
        o[4] = (__bf16)f1.x; o[5] = (__bf16)f1.y; o[6] = (__bf16)f1.z; o[7] = (__bf16)f1.w;
        *(bf16x8*)(a.dst[s] + r * 8) = o;
    }
}

// ---------------------------------------------------------------------------
// m97-style GEMM core, BK=64 as two BK=32 halves per barrier pair.
// 128x128 tile, 256 threads (2x2 waves of 64x64), global_load_lds width=16.
// ---------------------------------------------------------------------------
template <typename EPI>
static __device__ __forceinline__ void gemm128_core(
    const __bf16* __restrict__ A, const __bf16* __restrict__ Bw,
    int m0, int n0, __bf16* As, __bf16* Bs, EPI epi)
{
    const int t    = threadIdx.x;
    const int w    = t >> 6, lane = t & 63;
    const int lrow = lane & 15, quad = lane >> 4;
    const int lr   = lane >> 2, lc = lane & 3;   // 16 rows x 4 16B-chunks

    floatx4 acc[4][4];
    #pragma unroll
    for (int mi = 0; mi < 4; mi++)
        #pragma unroll
        for (int ni = 0; ni < 4; ni++) acc[mi][ni] = floatx4{0.f, 0.f, 0.f, 0.f};

    const __bf16* ga = A  + (size_t)(m0 + w * 32 + lr) * 1024 + lc * 8;
    const __bf16* gb = Bw + (size_t)(n0 + w * 32 + lr) * 1024 + lc * 8;

    for (int k0 = 0; k0 < 1024; k0 += 64) {
        __syncthreads();
        #pragma unroll
        for (int h = 0; h < 2; h++) {
            gl_lds(ga + k0 + h * 32,             &As[h * 4096 + (w * 32) * 32],      lane);
            gl_lds(ga + k0 + h * 32 + 16 * 1024, &As[h * 4096 + (w * 32 + 16) * 32], lane);
            gl_lds(gb + k0 + h * 32,             &Bs[h * 4096 + (w * 32) * 32],      lane);
            gl_lds(gb + k0 + h * 32 + 16 * 1024, &Bs[h * 4096 + (w * 32 + 16) * 32], lane);
        }
        __syncthreads();

        #pragma unroll
        for (int h = 0; h < 2; h++) {
            bf16x8 af[4], bfr[4];
            #pragma unroll
            for (int mi = 0; mi < 4; mi++)
                af[mi] = *(const bf16x8*)
                    &As[h * 4096 + ((w & 1) * 64 + mi * 16 + lrow) * 32 + quad * 8];
            #pragma unroll
            for (int ni = 0; ni < 4; ni++)
                bfr[ni] = *(const bf16x8*)
                    &Bs[h * 4096 + ((w >> 1) * 64 + ni * 16 + lrow) * 32 + quad * 8];
            #pragma unroll
            for (int mi = 0; mi < 4; mi++)
                #pragma unroll
                for (int ni = 0; ni < 4; ni++)
                    acc[mi][ni] = mfma16(af[mi], bfr[ni], acc[mi][ni]);
        }
    }

    #pragma unroll
    for (int mi = 0; mi < 4; mi++)
        #pragma unroll
        for (int ni = 0; ni < 4; ni++)
            #pragma unroll
            for (int r = 0; r < 4; r++) {
                const int m = m0 + (w & 1) * 64 + mi * 16 + quad * 4 + r;
                const int n = n0 + (w >> 1) * 64 + ni * 16 + lrow;
                epi(m, n, acc[mi][ni][r]);
            }
}

// 32x128-tile variant for oproj (previous-session-proven shape): grid (64,8)
// = 512 blocks = 2 blocks/CU.
template <typename EPI>
static __device__ __forceinline__ void gemm32_core(
    const __bf16* __restrict__ A, const __bf16* __restrict__ Bw,
    int m0, int n0, EPI epi)
{
    __shared__ alignas(16) __bf16 As[2][32 * 32];
    __shared__ alignas(16) __bf16 Bs[2][128 * 32];
    const int t    = threadIdx.x;
    const int w    = t >> 6, lane = t & 63;
    const int lrow = lane & 15, quad = lane >> 4;
    const int lr   = lane >> 2, lc = lane & 3;

    floatx4 acc[2][2];
    #pragma unroll
    for (int mi = 0; mi < 2; mi++)
        #pragma unroll
        for (int ni = 0; ni < 2; ni++) acc[mi][ni] = floatx4{0.f, 0.f, 0.f, 0.f};

    const __bf16* ga = A  + (size_t)(m0 + (w & 1) * 16 + lr) * 1024 + lc * 8;
    const __bf16* gb = Bw + (size_t)(n0 + w * 32 + lr) * 1024 + lc * 8;

    for (int k0 = 0; k0 < 1024; k0 += 64) {
        __syncthreads();
        #pragma unroll
        for (int h = 0; h < 2; h++) {
            if (w < 2)
                gl_lds(ga + k0 + h * 32, &As[h][(w * 16) * 32], lane);
            gl_lds(gb + k0 + h * 32,             &Bs[h][(w * 32) * 32],      lane);
            gl_lds(gb + k0 + h * 32 + 16 * 1024, &Bs[h][(w * 32 + 16) * 32], lane);
        }
        __syncthreads();

        #pragma unroll
        for (int h = 0; h < 2; h++) {
            bf16x8 af[2], bfr[2];
            #pragma unroll
            for (int mi = 0; mi < 2; mi++)
                af[mi] = *(const bf16x8*)
                    &As[h][(mi * 16 + lrow) * 32 + quad * 8];
            #pragma unroll
            for (int ni = 0; ni < 2; ni++)
                bfr[ni] = *(const bf16x8*)
                    &Bs[h][(w * 32 + ni * 16 + lrow) * 32 + quad * 8];
            #pragma unroll
            for (int mi = 0; mi < 2; mi++)
                #pragma unroll
                for (int ni = 0; ni < 2; ni++)
                    acc[mi][ni] = mfma16(af[mi], bfr[ni], acc[mi][ni]);
        }
    }

    #pragma unroll
    for (int mi = 0; mi < 2; mi++)
        #pragma unroll
        for (int ni = 0; ni < 2; ni++)
            #pragma unroll
            for (int r = 0; r < 4; r++) {
                const int m = m0 + mi * 16 + quad * 4 + r;
                const int n = n0 + w * 32 + ni * 16 + lrow;
                epi(m, n, acc[mi][ni][r]);
            }
}

// Fused projection kernel: z = 0 -> qp, 1 -> kp, 2 -> vpT (operand-swapped).
// R12: XCD-aware (x,y) swizzle. Dispatch assigns XCD = blockIdx-linear % 8
// = x % 8 (y,z contribute multiples of 8). Remap so each XCD owns ONE
// B col-band: ys = x & 7 (band), xs = (x>>3) | (y<<2)  (bijective 32x8).
// All blocks on an XCD share n0 -> the 256 KB weight band stays in that
// XCD's L2 across its 32 A-bands (was: round-robin pulled every band into
// all 8 L2s; R11 counters showed proj latency-bound, everything idle).
__global__ __launch_bounds__(256) void proj_kernel(
    const __bf16* __restrict__ qb, const __bf16* __restrict__ kb,
    const __bf16* __restrict__ vb, const __bf16* __restrict__ wqb,
    const __bf16* __restrict__ wkb, const __bf16* __restrict__ wvb,
    __bf16* __restrict__ qp, __bf16* __restrict__ kp,
    __bf16* __restrict__ vpT)
{
    __shared__ alignas(16) __bf16 As[2 * 128 * 32];
    __shared__ alignas(16) __bf16 Bs[2 * 128 * 32];
    const int z  = blockIdx.z;
    const int ys = blockIdx.x & 7;                        // B col-band
    const int xs = (blockIdx.x >> 3) | (blockIdx.y << 2); // A row-band
    if (z == 0) {
        if (xs >= 16) return;             // q has 16 m-tiles (2048 rows)
        gemm128_core(qb, wqb, xs * 128, ys * 128, As, Bs,
                     [&](int m, int n, float v) {
            const int b = m >> 10, q = m & 1023;
            const int h = n >> 6,  d = n & 63;
            qp[(((size_t)(b * 16 + h) * NQ_ + q) << 6) + d] = (__bf16)v;
        });
    } else if (z == 1) {
        gemm128_core(kb, wkb, xs * 128, ys * 128, As, Bs,
                     [&](int m, int n, float v) {
            const int b = m >> 11, key = m & 2047;
            const int h = n >> 6,  d = n & 63;
            kp[(((size_t)(b * 16 + h) * NK_ + key) << 6) + d] = (__bf16)v;
        });
    } else {
        // swapped: A = Wv (rows = hd), B = V (rows = keys)
        gemm128_core(wvb, vb, ys * 128, xs * 128, As, Bs,
                     [&](int m, int n, float v) {
            const int h = m >> 6,  d = m & 63;
            const int b = n >> 11, key = n & 2047;
            vpT[((size_t)(b * 16 + h) * HD_ + d) * VPAD + key] = (__bf16)v;
        });
    }
}

// Output projection: attnout(2048x1024 bf16) x Wo^T -> d_out f32.
// R12: XCD swizzle — ys = x & 7 (Wo col-band, one per XCD), xs = (x>>3)|(y<<3).
__global__ __launch_bounds__(256) void oproj_kernel(
    const __bf16* __restrict__ A, const __bf16* __restrict__ W,
    float* __restrict__ Cout)
{
    const int ys = blockIdx.x & 7;
    const int xs = (blockIdx.x >> 3) | (blockIdx.y << 3);   // 0..63
    gemm32_core(A, W, xs * 32, ys * 128, [&](int m, int n, float v) {
        Cout[(size_t)m * 1024 + n] = v;
    });
}

// ---------------------------------------------------------------------------
// Fused attention, split-K (2 halves), 32 q-rows/wave — EXACT R5 kernel
// (best measured attn: 47.7-49.7 us). kf/vf fragment reads SHARED across the
// two Q row-groups (DS/MFMA = 1.0); 2 barriers/tile; Vt[2] double-buffer;
// prefetch loads issued right after barrier-2 (full tile before next drain).
// Grid 512 = 8 qt x 32 bh x 2 k-halves; 2 blocks/CU resident, single round.
// ---------------------------------------------------------------------------
__global__ __launch_bounds__(256, 2) void attn_kernel(
    const __bf16* __restrict__ qp, const __bf16* __restrict__ kp,
    const __bf16* __restrict__ vpT, const __bf16* __restrict__ dmask,
    const float* __restrict__ msum, const float* __restrict__ galpha,
    float* __restrict__ Opart, float* __restrict__ Gpart)
{
    __shared__ __bf16 Ks[64 * 72];
    __shared__ __bf16 Vt[2][64 * 72];
    __shared__ __bf16 Ps[4][32 * 72];
    const int t    = threadIdx.x;
    const int w    = t >> 6, lane = t & 63;
    const int lrow = lane & 15, quad = lane >> 4;
    const int bid  = ((blockIdx.x & 7) << 6) | (blockIdx.x >> 3); // XCD swizzle
    const int qt   = bid & 7;             // 0..7   (128-row q tiles)
    const int bh   = (bid >> 3) & 31;     // 0..31
    const int z    = bid >> 8;            // 0..1 k-half
    const int b    = bh >> 4, h = bh & 15;
    const int q0   = qt * 128 + w * 32;   // wave's 32-row base
    const int kb0  = z * (NK_ / 2);
    const int NT   = NK_ / 128;           // 16 tiles of 64 keys

    const float mean  = fmaxf(msum[b] / ((float)(NQ_ * NK_) + 1e-6f), 1e-6f);
    const float alpha = log1pf(__expf(galpha[0]));
    const float cg    = -alpha / mean;    // strictly negative

    // Q fragments for both 16-row groups
    bf16x8 qf0[2], qf1[2];
    #pragma unroll
    for (int g = 0; g < 2; g++) {
        const __bf16* qb = qp + ((size_t)bh * NQ_ + q0 + g * 16 + lrow) * HD_
                         + quad * 8;
        qf0[g] = *(const bf16x8*)qb;
        qf1[g] = *(const bf16x8*)(qb + 32);
    }

    const int srow0 = t >> 3,        sc0 = t & 7;
    const int srow1 = 32 + (t >> 3), sc1 = t & 7;
    const int so0 = srow0 * 72 + sc0 * 8;
    const int so1 = srow1 * 72 + sc1 * 8;
    const __bf16* Kg = kp  + ((size_t)bh * NK_ + kb0) * HD_;
    const __bf16* Vg = vpT + (size_t)bh * HD_ * VPAD + kb0;
    const __bf16* grow0 = dmask + ((size_t)b * NQ_ + q0 + lrow) * GPAD + kb0;
    const __bf16* grow1 = grow0 + (size_t)16 * GPAD;

    float G[2] = {0.f, 0.f};
    floatx4 O[2][4];
    #pragma unroll
    for (int g = 0; g < 2; g++)
        #pragma unroll
        for (int nb = 0; nb < 4; nb++) O[g][nb] = floatx4{0.f, 0.f, 0.f, 0.f};

    bf16x8 kr0, kr1, vr0, vr1;
    bf16x4 gr[2][4];
    auto loadt = [&](int kb) {
        kr0 = *(const bf16x8*)(Kg + (size_t)(kb + srow0) * HD_ + sc0 * 8);
        kr1 = *(const bf16x8*)(Kg + (size_t)(kb + srow1) * HD_ + sc1 * 8);
        vr0 = *(const bf16x8*)(Vg + (size_t)srow0 * VPAD + kb + sc0 * 8);
        vr1 = *(const bf16x8*)(Vg + (size_t)srow1 * VPAD + kb + sc1 * 8);
        #pragma unroll
        for (int c = 0; c < 4; c++) {
            gr[0][c] = *(const bf16x4*)(grow0 + kb + c * 16 + quad * 4);
            gr[1][c] = *(const bf16x4*)(grow1 + kb + c * 16 + quad * 4);
        }
    };
    loadt(0);

    for (int ib = 0; ib < NT; ib++) {
        const int kb  = ib * 64;
        const int cur = ib & 1;

        __syncthreads();                  // prior Ks / Vt[cur] reads complete
        *(bf16x8*)&Ks[so0]      = kr0;
        *(bf16x8*)&Ks[so1]      = kr1;
        *(bf16x8*)&Vt[cur][so0] = vr0;
        *(bf16x8*)&Vt[cur][so1] = vr1;
        __syncthreads();                  // staging visible

        bf16x4 gcur[2][4];
        #pragma unroll
        for (int g = 0; g < 2; g++)
            #pragma unroll
            for (int c = 0; c < 4; c++) gcur[g][c] = gr[g][c];
        if (ib + 1 < NT) loadt(kb + 64);  // full tile before next drain

        __builtin_amdgcn_s_setprio(1);
        // --- QK(i): kf shared across both Q groups ---
        floatx4 s4[2][4];
        #pragma unroll
        for (int c = 0; c < 4; c++) {
            bf16x8 kf0 = *(const bf16x8*)&Ks[(c * 16 + lrow) * 72 + quad * 8];
            bf16x8 kf1 = *(const bf16x8*)&Ks[(c * 16 + lrow) * 72 + 32 + quad * 8];
            #pragma unroll
            for (int g = 0; g < 2; g++) {
                floatx4 a = floatx4{0.f, 0.f, 0.f, 0.f};
                a = mfma16(kf0, qf0[g], a);
                a = mfma16(kf1, qf1[g], a);
                s4[g][c] = a;
            }
        }

        // --- PV(i-1): vf shared across both P groups ---
        if (ib > 0) {
            const int prv = cur ^ 1;
            bf16x8 pf0[2], pf1[2];
            #pragma unroll
            for (int g = 0; g < 2; g++) {
                pf0[g] = *(const bf16x8*)&Ps[w][(g * 16 + lrow) * 72 + quad * 8];
                pf1[g] = *(const bf16x8*)&Ps[w][(g * 16 + lrow) * 72 + 32 + quad * 8];
            }
            #pragma unroll
            for (int nb = 0; nb < 4; nb++) {
                bf16x8 vf0 = *(const bf16x8*)
                    &Vt[prv][(nb * 16 + lrow) * 72 + quad * 8];
                bf16x8 vf1 = *(const bf16x8*)
                    &Vt[prv][(nb * 16 + lrow) * 72 + 32 + quad * 8];
                #pragma unroll
                for (int g = 0; g < 2; g++) {
                    O[g][nb] = mfma16(pf0[g], vf0, O[g][nb]);
                    O[g][nb] = mfma16(pf1[g], vf1, O[g][nb]);
                }
            }
        }
        __builtin_amdgcn_s_setprio(0);

        // --- exp(i): eg = exp(s/8 + c*d) -> Ps (single-buffered; PV-read ->
        // exp-write are same-wave DS ops, retired in order) ---
        #pragma unroll
        for (int g = 0; g < 2; g++)
            #pragma unroll
            for (int c = 0; c < 4; c++) {
                const float e0 = __expf(fmaf(s4[g][c][0], 0.125f, cg * (float)gcur[g][c][0]));
                const float e1 = __expf(fmaf(s4[g][c][1], 0.125f, cg * (float)gcur[g][c][1]));
                const float e2 = __expf(fmaf(s4[g][c][2], 0.125f, cg * (float)gcur[g][c][2]));
                const float e3 = __expf(fmaf(s4[g][c][3], 0.125f, cg * (float)gcur[g][c][3]));
                G[g] += (e0 + e1) + (e2 + e3);
                bf16x4 pk;
                pk[0] = (__bf16)e0; pk[1] = (__bf16)e1;
                pk[2] = (__bf16)e2; pk[3] = (__bf16)e3;
                *(bf16x4*)&Ps[w][(g * 16 + lrow) * 72 + c * 16 + quad * 4] = pk;
            }
    }

    // --- final PV(NT-1) ---
    {
        const int prv = (NT - 1) & 1;
        bf16x8 pf0[2], pf1[2];
        #pragma unroll
        for (int g = 0; g < 2; g++) {
            pf0[g] = *(const bf16x8*)&Ps[w][(g * 16 + lrow) * 72 + quad * 8];
            pf1[g] = *(const bf16x8*)&Ps[w][(g * 16 + lrow) * 72 + 32 + quad * 8];
        }
        #pragma unroll
        for (int nb = 0; nb < 4; nb++) {
            bf16x8 vf0 = *(const bf16x8*)&Vt[prv][(nb * 16 + lrow) * 72 + quad * 8];
            bf16x8 vf1 = *(const bf16x8*)&Vt[prv][(nb * 16 + lrow) * 72 + 32 + quad * 8];
            #pragma unroll
            for (int g = 0; g < 2; g++) {
                O[g][nb] = mfma16(pf0[g], vf0, O[g][nb]);
                O[g][nb] = mfma16(pf1[g], vf1, O[g][nb]);
            }
        }
    }

    // Partial G per group: reduce across quads; raw f32 partials out.
    #pragma unroll
    for (int g = 0; g < 2; g++) {
        G[g] += __shfl_xor(G[g], 16);
        G[g] += __shfl_xor(G[g], 32);
    }

    #pragma unroll
    for (int g = 0; g < 2; g++) {
        float* Op = Opart + (size_t)z * (B_ * NQ_ * 1024)
                          + ((size_t)b * NQ_ + q0 + g * 16) * 1024 + h * HD_;
        #pragma unroll
        for (int r = 0; r < 4; r++) {
            const int qr = quad * 4 + r;
            #pragma unroll
            for (int nb = 0; nb < 4; nb++)
                Op[(size_t)qr * 1024 + nb * 16 + lrow] = O[g][nb][r];
        }
        if (lane < 16)
            Gpart[(size_t)z * (32 * 1024) + bh * 1024 + q0 + g * 16 + lane] = G[g];
    }
}

// Combine the two k-half partials: attnout = (O0+O1) * kpm_q / (G0+G1).
// 2048 x 1024 elements, 4 cols/thread -> 2048 blocks. ~21 MB traffic.
__global__ __launch_bounds__(256) void combine_kernel(
    const float* __restrict__ Opart, const float* __restrict__ Gpart,
    const int* __restrict__ kpmq, __bf16* __restrict__ attnout)
{
    const int idx = blockIdx.x * 256 + threadIdx.x;   // 0..524287
    const int m   = idx >> 8;            // row 0..2047
    const int c4  = (idx & 255) * 4;     // col 0..1020
    const int b   = m >> 10, q = m & 1023;
    const int h   = c4 >> 6;
    const float g = Gpart[(b * 16 + h) * 1024 + q]
                  + Gpart[32 * 1024 + (b * 16 + h) * 1024 + q];
    const float f = kpmq[b * NQ_ + q] ? 1.f / (g + 1e-30f) : 0.f;
    const float4 o0 = *(const float4*)(Opart + (size_t)m * 1024 + c4);
    const float4 o1 = *(const float4*)(Opart + (size_t)(B_ * NQ_) * 1024
                                              + (size_t)m * 1024 + c4);
    bf16x4 r;
    r[0] = (__bf16)((o0.x + o1.x) * f);
    r[1] = (__bf16)((o0.y + o1.y) * f);
    r[2] = (__bf16)((o0.z + o1.z) * f);
    r[3] = (__bf16)((o0.w + o1.w) * f);
    *(bf16x4*)&attnout[(size_t)m * 1024 + c4] = r;
}

// ---------------------------------------------------------------------------
extern "C" void kernel_launch(void* const* d_in, const int* in_sizes, int n_in,
                              void* d_out, int out_size, void* d_ws,
                              size_t ws_size, hipStream_t stream)
{
    const float* q      = (const float*)d_in[0];
    const float* k      = (const float*)d_in[1];
    const float* v      = (const float*)d_in[2];
    const float* dist   = (const float*)d_in[3];
    const int*   amask  = (const int*)d_in[4];
    const int*   kpmq   = (const int*)d_in[5];
    const int*   kpmk   = (const int*)d_in[6];
    const float* Wq     = (const float*)d_in[7];
    const float* Wk     = (const float*)d_in[8];
    const float* Wv     = (const float*)d_in[9];
    const float* Wo     = (const float*)d_in[10];
    const float* galpha = (const float*)d_in[11];

    char* p = (char*)d_ws;
    float*  msum = (float*)p;                 p += 256;
    __bf16* qb   = (__bf16*)p;                p += (size_t)2097152 * 2;
    __bf16* kb   = (__bf16*)p;                p += (size_t)4194304 * 2;
    __bf16* vb   = (__bf16*)p;                p += (size_t)4194304 * 2;
    __bf16* wqb  = (__bf16*)p;                p += (size_t)1048576 * 2;
    __bf16* wkb  = (__bf16*)p;                p += (size_t)1048576 * 2;
    __bf16* wvb  = (__bf16*)p;                p += (size_t)1048576 * 2;
    __bf16* wob  = (__bf16*)p;                p += (size_t)1048576 * 2;
    __bf16* qp   = (__bf16*)p;                p += (size_t)2097152 * 2;
    __bf16* kpb  = (__bf16*)p;                p += (size_t)4194304 * 2;
    __bf16* vpT  = (__bf16*)p;                p += (size_t)32 * 64 * VPAD * 2;
    __bf16* dmask = (__bf16*)p;               p += (size_t)2048 * GPAD * 2;
    __bf16* attnout = (__bf16*)p;             p += (size_t)2097152 * 2;

    // Split-K partial buffers OVERLAY the bf16 staging buffers, which are
    // dead after proj_kernel: Opart (16 MiB) on kb+vb (contiguous 16 MiB),
    // Gpart (256 KiB) on qb (4 MiB). Stream-ordered, so no hazard.
    float* Opart = (float*)kb;
    float* Gpart = (float*)qb;

    CvtArgs ca;
    ca.src[0] = q;  ca.src[1] = k;  ca.src[2] = v;
    ca.src[3] = Wq; ca.src[4] = Wk; ca.src[5] = Wv; ca.src[6] = Wo;
    ca.dst[0] = qb;  ca.dst[1] = kb;  ca.dst[2] = vb;
    ca.dst[3] = wqb; ca.dst[4] = wkb; ca.dst[5] = wvb; ca.dst[6] = wob;

    hipMemsetAsync(msum, 0, 256, stream);
    cvt_mean_kernel<<<2816, 256, 0, stream>>>(ca, dist, amask, kpmk, msum,
                                              dmask);
    proj_kernel<<<dim3(32, 8, 3), 256, 0, stream>>>(qb, kb, vb, wqb, wkb, wvb,
                                                    qp, kpb, vpT);
    attn_kernel<<<512, 256, 0, stream>>>(qp, kpb, vpT, dmask,
                                         msum, galpha, Opart, Gpart);
    combine_kernel<<<2048, 256, 0, stream>>>(Opart, Gpart, kpmq, attnout);
    oproj_kernel<<<dim3(64, 8), 256, 0, stream>>>(attnout, wob, (float*)d_out);
}

// Round 13
// 238.508 us; speedup vs baseline: 1.0912x; 1.0432x over previous
//
#include <hip/hip_runtime.h>
#include <hip/hip_bf16.h>
#include <cfloat>

#define B_   2
#define NQ_  1024
#define NK_  2048
#define H_   16
#define HD_  64
#define VPAD 2176      // vpT row stride in bf16 elements
#define GPAD 2112      // dmask row stride in bf16 elements

typedef float  floatx4 __attribute__((ext_vector_type(4)));
typedef __bf16 bf16x8  __attribute__((ext_vector_type(8)));
typedef __bf16 bf16x4  __attribute__((ext_vector_type(4)));

static __device__ __forceinline__ floatx4 mfma16(bf16x8 a, bf16x8 b, floatx4 c) {
    return __builtin_amdgcn_mfma_f32_16x16x32_bf16(a, b, c, 0, 0, 0);
}

// global -> LDS direct copy, 16B per lane. lbase wave-uniform.
static __device__ __forceinline__ void gl_lds(const __bf16* g, __bf16* lbase,
                                              int lane) {
#if __has_builtin(__builtin_amdgcn_global_load_lds)
    __builtin_amdgcn_global_load_lds(
        (const __attribute__((address_space(1))) void*)g,
        (__attribute__((address_space(3))) void*)lbase, 16, 0, 0);
#else
    *(bf16x8*)(lbase + lane * 8) = *(const bf16x8*)g;
#endif
}

// ---------------------------------------------------------------------------
// Kernel 0 (R13 slim): f32->bf16 conversion of q/k/v + weights only.
// The dmask/masked-sum pass moved into proj_dm_kernel (overlaps with proj).
// 1792 blocks x 256 threads x 4 groups = 1835008 groups of 8.
// ---------------------------------------------------------------------------
struct CvtArgs {
    const float* src[7];
    __bf16*      dst[7];
};

__global__ __launch_bounds__(256) void cvt_kernel(CvtArgs a)
{
    #pragma unroll
    for (int j = 0; j < 4; j++) {
        size_t r = (size_t)blockIdx.x * 1024 + j * 256 + threadIdx.x;
        int s;
        if (r < 262144)                  { s = 0; }
        else if ((r -= 262144) < 524288) { s = 1; }
        else if ((r -= 524288) < 524288) { s = 2; }
        else { r -= 524288; s = 3 + (int)(r >> 17); r &= 131071; }
        const float* sp = a.src[s] + r * 8;
        float4 f0 = *(const float4*)sp;
        float4 f1 = *(const float4*)(sp + 4);
        bf16x8 o;
        o[0] = (__bf16)f0.x; o[1] = (__bf16)f0.y; o[2] = (__bf16)f0.z; o[3] = (__bf16)f0.w;
        o[4] = (__bf16)f1.x; o[5] = (__bf16)f1.y; o[6] = (__bf16)f1.z; o[7] = (__bf16)f1.w;
        *(bf16x8*)(a.dst[s] + r * 8) = o;
    }
}

// ---------------------------------------------------------------------------
// m97-style GEMM core, BK=64 as two BK=32 halves per barrier pair.
// 128x128 tile, 256 threads (2x2 waves of 64x64), global_load_lds width=16.
// ---------------------------------------------------------------------------
template <typename EPI>
static __device__ __forceinline__ void gemm128_core(
    const __bf16* __restrict__ A, const __bf16* __restrict__ Bw,
    int m0, int n0, __bf16* As, __bf16* Bs, EPI epi)
{
    const int t    = threadIdx.x;
    const int w    = t >> 6, lane = t & 63;
    const int lrow = lane & 15, quad = lane >> 4;
    const int lr   = lane >> 2, lc = lane & 3;   // 16 rows x 4 16B-chunks

    floatx4 acc[4][4];
    #pragma unroll
    for (int mi = 0; mi < 4; mi++)
        #pragma unroll
        for (int ni = 0; ni < 4; ni++) acc[mi][ni] = floatx4{0.f, 0.f, 0.f, 0.f};

    const __bf16* ga = A  + (size_t)(m0 + w * 32 + lr) * 1024 + lc * 8;
    const __bf16* gb = Bw + (size_t)(n0 + w * 32 + lr) * 1024 + lc * 8;

    for (int k0 = 0; k0 < 1024; k0 += 64) {
        __syncthreads();
        #pragma unroll
        for (int h = 0; h < 2; h++) {
            gl_lds(ga + k0 + h * 32,             &As[h * 4096 + (w * 32) * 32],      lane);
            gl_lds(ga + k0 + h * 32 + 16 * 1024, &As[h * 4096 + (w * 32 + 16) * 32], lane);
            gl_lds(gb + k0 + h * 32,             &Bs[h * 4096 + (w * 32) * 32],      lane);
            gl_lds(gb + k0 + h * 32 + 16 * 1024, &Bs[h * 4096 + (w * 32 + 16) * 32], lane);
        }
        __syncthreads();

        #pragma unroll
        for (int h = 0; h < 2; h++) {
            bf16x8 af[4], bfr[4];
            #pragma unroll
            for (int mi = 0; mi < 4; mi++)
                af[mi] = *(const bf16x8*)
                    &As[h * 4096 + ((w & 1) * 64 + mi * 16 + lrow) * 32 + quad * 8];
            #pragma unroll
            for (int ni = 0; ni < 4; ni++)
                bfr[ni] = *(const bf16x8*)
                    &Bs[h * 4096 + ((w >> 1) * 64 + ni * 16 + lrow) * 32 + quad * 8];
            #pragma unroll
            for (int mi = 0; mi < 4; mi++)
                #pragma unroll
                for (int ni = 0; ni < 4; ni++)
                    acc[mi][ni] = mfma16(af[mi], bfr[ni], acc[mi][ni]);
        }
    }

    #pragma unroll
    for (int mi = 0; mi < 4; mi++)
        #pragma unroll
        for (int ni = 0; ni < 4; ni++)
            #pragma unroll
            for (int r = 0; r < 4; r++) {
                const int m = m0 + (w & 1) * 64 + mi * 16 + quad * 4 + r;
                const int n = n0 + (w >> 1) * 64 + ni * 16 + lrow;
                epi(m, n, acc[mi][ni][r]);
            }
}

// 32x128-tile variant for oproj: grid (64,8) = 512 blocks = 2 blocks/CU.
template <typename EPI>
static __device__ __forceinline__ void gemm32_core(
    const __bf16* __restrict__ A, const __bf16* __restrict__ Bw,
    int m0, int n0, EPI epi)
{
    __shared__ alignas(16) __bf16 As[2][32 * 32];
    __shared__ alignas(16) __bf16 Bs[2][128 * 32];
    const int t    = threadIdx.x;
    const int w    = t >> 6, lane = t & 63;
    const int lrow = lane & 15, quad = lane >> 4;
    const int lr   = lane >> 2, lc = lane & 3;

    floatx4 acc[2][2];
    #pragma unroll
    for (int mi = 0; mi < 2; mi++)
        #pragma unroll
        for (int ni = 0; ni < 2; ni++) acc[mi][ni] = floatx4{0.f, 0.f, 0.f, 0.f};

    const __bf16* ga = A  + (size_t)(m0 + (w & 1) * 16 + lr) * 1024 + lc * 8;
    const __bf16* gb = Bw + (size_t)(n0 + w * 32 + lr) * 1024 + lc * 8;

    for (int k0 = 0; k0 < 1024; k0 += 64) {
        __syncthreads();
        #pragma unroll
        for (int h = 0; h < 2; h++) {
            if (w < 2)
                gl_lds(ga + k0 + h * 32, &As[h][(w * 16) * 32], lane);
            gl_lds(gb + k0 + h * 32,             &Bs[h][(w * 32) * 32],      lane);
            gl_lds(gb + k0 + h * 32 + 16 * 1024, &Bs[h][(w * 32 + 16) * 32], lane);
        }
        __syncthreads();

        #pragma unroll
        for (int h = 0; h < 2; h++) {
            bf16x8 af[2], bfr[2];
            #pragma unroll
            for (int mi = 0; mi < 2; mi++)
                af[mi] = *(const bf16x8*)
                    &As[h][(mi * 16 + lrow) * 32 + quad * 8];
            #pragma unroll
            for (int ni = 0; ni < 2; ni++)
                bfr[ni] = *(const bf16x8*)
                    &Bs[h][(w * 32 + ni * 16 + lrow) * 32 + quad * 8];
            #pragma unroll
            for (int mi = 0; mi < 2; mi++)
                #pragma unroll
                for (int ni = 0; ni < 2; ni++)
                    acc[mi][ni] = mfma16(af[mi], bfr[ni], acc[mi][ni]);
        }
    }

    #pragma unroll
    for (int mi = 0; mi < 2; mi++)
        #pragma unroll
        for (int ni = 0; ni < 2; ni++)
            #pragma unroll
            for (int r = 0; r < 4; r++) {
                const int m = m0 + mi * 16 + quad * 4 + r;
                const int n = n0 + w * 32 + ni * 16 + lrow;
                epi(m, n, acc[mi][ni][r]);
            }
}

// ---------------------------------------------------------------------------
// Fused projection + dmask kernel (R13). Blocks 0..767: the three proj
// GEMMs (latency-bound: MfmaUtil 12%, VALU 7%, HBM 13% — R11 counters).
// Blocks 768..1791: the dmask/masked-sum streaming pass (depends only on
// kernel INPUTS, and proj doesn't read dmask/msum -> safe to co-schedule).
// The streaming blocks back-fill the 4th LDS slot per CU and use the HBM
// bandwidth proj leaves idle. wsum aliases As to keep LDS at exactly 32 KB
// (4-blocks/CU pool boundary). XCD mapping: proj lin&7 = col-band = XCD.
// ---------------------------------------------------------------------------
__global__ __launch_bounds__(256) void proj_dm_kernel(
    const __bf16* __restrict__ qb, const __bf16* __restrict__ kb,
    const __bf16* __restrict__ vb, const __bf16* __restrict__ wqb,
    const __bf16* __restrict__ wkb, const __bf16* __restrict__ wvb,
    __bf16* __restrict__ qp, __bf16* __restrict__ kp,
    __bf16* __restrict__ vpT,
    const float* __restrict__ dist, const int* __restrict__ amask,
    const int* __restrict__ kpmk, float* __restrict__ msum,
    __bf16* __restrict__ dmask)
{
    __shared__ alignas(16) __bf16 As[2 * 128 * 32];
    __shared__ alignas(16) __bf16 Bs[2 * 128 * 32];
    const int lin = blockIdx.x;

    if (lin >= 768) {
        // ---- dmask + masked distance sum (1024 streaming blocks) ----
        const int mb = lin - 768;              // 0..1023
        const int b  = mb >> 9;                // 0..1
        const float* d  = dist  + (size_t)b * NQ_ * NK_;
        const int*   am = amask + (size_t)b * NQ_ * NK_;
        const int*   km = kpmk  + b * NK_;
        __bf16*      dm = dmask + (size_t)b * NQ_ * GPAD;
        const int base = (mb & 511) * 256 + threadIdx.x;   // 0..131071
        float s = 0.f;
        #pragma unroll
        for (int j = 0; j < 4; j++) {
            const int i   = base + j * 131072;
            const int idx = i * 4;
            const int kk  = idx & (NK_ - 1);
            const int q   = i >> 9;
            float4 dv = *(const float4*)(d + idx);
            int4   mv = *(const int4*)(am + idx);
            int4   kv = *(const int4*)(km + kk);
            bf16x4 o;
            if (mv.x && kv.x) { s += dv.x; o[0] = (__bf16)dv.x; } else o[0] = (__bf16)3e38f;
            if (mv.y && kv.y) { s += dv.y; o[1] = (__bf16)dv.y; } else o[1] = (__bf16)3e38f;
            if (mv.z && kv.z) { s += dv.z; o[2] = (__bf16)dv.z; } else o[2] = (__bf16)3e38f;
            if (mv.w && kv.w) { s += dv.w; o[3] = (__bf16)dv.w; } else o[3] = (__bf16)3e38f;
            *(bf16x4*)&dm[(size_t)q * GPAD + kk] = o;
        }
        #pragma unroll
        for (int off = 32; off >= 1; off >>= 1) s += __shfl_down(s, off);
        float* wsum = (float*)As;              // alias: keeps LDS at 32 KB
        if ((threadIdx.x & 63) == 0) wsum[threadIdx.x >> 6] = s;
        __syncthreads();
        if (threadIdx.x == 0)
            atomicAdd(&msum[b], wsum[0] + wsum[1] + wsum[2] + wsum[3]);
        return;
    }

    // ---- proj part (768 blocks): lin&7 = col-band ys = XCD ----
    const int ys   = lin & 7;
    const int rest = lin >> 3;        // 0..95
    const int xs   = rest & 31;
    const int z    = rest >> 5;       // 0..2
    if (z == 0) {
        if (xs >= 16) return;         // q has 16 m-tiles (2048 rows)
        gemm128_core(qb, wqb, xs * 128, ys * 128, As, Bs,
                     [&](int m, int n, float v) {
            const int b = m >> 10, q = m & 1023;
            const int h = n >> 6,  d = n & 63;
            qp[(((size_t)(b * 16 + h) * NQ_ + q) << 6) + d] = (__bf16)v;
        });
    } else if (z == 1) {
        gemm128_core(kb, wkb, xs * 128, ys * 128, As, Bs,
                     [&](int m, int n, float v) {
            const int b = m >> 11, key = m & 2047;
            const int h = n >> 6,  d = n & 63;
            kp[(((size_t)(b * 16 + h) * NK_ + key) << 6) + d] = (__bf16)v;
        });
    } else {
        // swapped: A = Wv (rows = hd), B = V (rows = keys)
        gemm128_core(wvb, vb, ys * 128, xs * 128, As, Bs,
                     [&](int m, int n, float v) {
            const int h = m >> 6,  d = m & 63;
            const int b = n >> 11, key = n & 2047;
            vpT[((size_t)(b * 16 + h) * HD_ + d) * VPAD + key] = (__bf16)v;
        });
    }
}

// Output projection: attnout(2048x1024 bf16) x Wo^T -> d_out f32.
// XCD swizzle — ys = x & 7 (Wo col-band, one per XCD), xs = (x>>3)|(y<<3).
__global__ __launch_bounds__(256) void oproj_kernel(
    const __bf16* __restrict__ A, const __bf16* __restrict__ W,
    float* __restrict__ Cout)
{
    const int ys = blockIdx.x & 7;
    const int xs = (blockIdx.x >> 3) | (blockIdx.y << 3);   // 0..63
    gemm32_core(A, W, xs * 32, ys * 128, [&](int m, int n, float v) {
        Cout[(size_t)m * 1024 + n] = v;
    });
}

// ---------------------------------------------------------------------------
// Fused attention, split-K (2 halves), 32 q-rows/wave — EXACT R5 kernel
// (best measured attn: 47.2-49.7 us). kf/vf fragment reads SHARED across the
// two Q row-groups (DS/MFMA = 1.0); 2 barriers/tile; Vt[2] double-buffer;
// prefetch loads issued right after barrier-2 (full tile before next drain).
// Grid 512 = 8 qt x 32 bh x 2 k-halves; 2 blocks/CU resident, single round.
// ---------------------------------------------------------------------------
__global__ __launch_bounds__(256, 2) void attn_kernel(
    const __bf16* __restrict__ qp, const __bf16* __restrict__ kp,
    const __bf16* __restrict__ vpT, const __bf16* __restrict__ dmask,
    const float* __restrict__ msum, const float* __restrict__ galpha,
    float* __restrict__ Opart, float* __restrict__ Gpart)
{
    __shared__ __bf16 Ks[64 * 72];
    __shared__ __bf16 Vt[2][64 * 72];
    __shared__ __bf16 Ps[4][32 * 72];
    const int t    = threadIdx.x;
    const int w    = t >> 6, lane = t & 63;
    const int lrow = lane & 15, quad = lane >> 4;
    const int bid  = ((blockIdx.x & 7) << 6) | (blockIdx.x >> 3); // XCD swizzle
    const int qt   = bid & 7;             // 0..7   (128-row q tiles)
    const int bh   = (bid >> 3) & 31;     // 0..31
    const int z    = bid >> 8;            // 0..1 k-half
    const int b    = bh >> 4, h = bh & 15;
    const int q0   = qt * 128 + w * 32;   // wave's 32-row base
    const int kb0  = z * (NK_ / 2);
    const int NT   = NK_ / 128;           // 16 tiles of 64 keys

    const float mean  = fmaxf(msum[b] / ((float)(NQ_ * NK_) + 1e-6f), 1e-6f);
    const float alpha = log1pf(__expf(galpha[0]));
    const float cg    = -alpha / mean;    // strictly negative

    // Q fragments for both 16-row groups
    bf16x8 qf0[2], qf1[2];
    #pragma unroll
    for (int g = 0; g < 2; g++) {
        const __bf16* qb = qp + ((size_t)bh * NQ_ + q0 + g * 16 + lrow) * HD_
                         + quad * 8;
        qf0[g] = *(const bf16x8*)qb;
        qf1[g] = *(const bf16x8*)(qb + 32);
    }

    const int srow0 = t >> 3,        sc0 = t & 7;
    const int srow1 = 32 + (t >> 3), sc1 = t & 7;
    const int so0 = srow0 * 72 + sc0 * 8;
    const int so1 = srow1 * 72 + sc1 * 8;
    const __bf16* Kg = kp  + ((size_t)bh * NK_ + kb0) * HD_;
    const __bf16* Vg = vpT + (size_t)bh * HD_ * VPAD + kb0;
    const __bf16* grow0 = dmask + ((size_t)b * NQ_ + q0 + lrow) * GPAD + kb0;
    const __bf16* grow1 = grow0 + (size_t)16 * GPAD;

    float G[2] = {0.f, 0.f};
    floatx4 O[2][4];
    #pragma unroll
    for (int g = 0; g < 2; g++)
        #pragma unroll
        for (int nb = 0; nb < 4; nb++) O[g][nb] = floatx4{0.f, 0.f, 0.f, 0.f};

    bf16x8 kr0, kr1, vr0, vr1;
    bf16x4 gr[2][4];
    auto loadt = [&](int kb) {
        kr0 = *(const bf16x8*)(Kg + (size_t)(kb + srow0) * HD_ + sc0 * 8);
        kr1 = *(const bf16x8*)(Kg + (size_t)(kb + srow1) * HD_ + sc1 * 8);
        vr0 = *(const bf16x8*)(Vg + (size_t)srow0 * VPAD + kb + sc0 * 8);
        vr1 = *(const bf16x8*)(Vg + (size_t)srow1 * VPAD + kb + sc1 * 8);
        #pragma unroll
        for (int c = 0; c < 4; c++) {
            gr[0][c] = *(const bf16x4*)(grow0 + kb + c * 16 + quad * 4);
            gr[1][c] = *(const bf16x4*)(grow1 + kb + c * 16 + quad * 4);
        }
    };
    loadt(0);

    for (int ib = 0; ib < NT; ib++) {
        const int kb  = ib * 64;
        const int cur = ib & 1;

        __syncthreads();                  // prior Ks / Vt[cur] reads complete
        *(bf16x8*)&Ks[so0]      = kr0;
        *(bf16x8*)&Ks[so1]      = kr1;
        *(bf16x8*)&Vt[cur][so0] = vr0;
        *(bf16x8*)&Vt[cur][so1] = vr1;
        __syncthreads();                  // staging visible

        bf16x4 gcur[2][4];
        #pragma unroll
        for (int g = 0; g < 2; g++)
            #pragma unroll
            for (int c = 0; c < 4; c++) gcur[g][c] = gr[g][c];
        if (ib + 1 < NT) loadt(kb + 64);  // full tile before next drain

        __builtin_amdgcn_s_setprio(1);
        // --- QK(i): kf shared across both Q groups ---
        floatx4 s4[2][4];
        #pragma unroll
        for (int c = 0; c < 4; c++) {
            bf16x8 kf0 = *(const bf16x8*)&Ks[(c * 16 + lrow) * 72 + quad * 8];
            bf16x8 kf1 = *(const bf16x8*)&Ks[(c * 16 + lrow) * 72 + 32 + quad * 8];
            #pragma unroll
            for (int g = 0; g < 2; g++) {
                floatx4 a = floatx4{0.f, 0.f, 0.f, 0.f};
                a = mfma16(kf0, qf0[g], a);
                a = mfma16(kf1, qf1[g], a);
                s4[g][c] = a;
            }
        }

        // --- PV(i-1): vf shared across both P groups ---
        if (ib > 0) {
            const int prv = cur ^ 1;
            bf16x8 pf0[2], pf1[2];
            #pragma unroll
            for (int g = 0; g < 2; g++) {
                pf0[g] = *(const bf16x8*)&Ps[w][(g * 16 + lrow) * 72 + quad * 8];
                pf1[g] = *(const bf16x8*)&Ps[w][(g * 16 + lrow) * 72 + 32 + quad * 8];
            }
            #pragma unroll
            for (int nb = 0; nb < 4; nb++) {
                bf16x8 vf0 = *(const bf16x8*)
                    &Vt[prv][(nb * 16 + lrow) * 72 + quad * 8];
                bf16x8 vf1 = *(const bf16x8*)
                    &Vt[prv][(nb * 16 + lrow) * 72 + 32 + quad * 8];
                #pragma unroll
                for (int g = 0; g < 2; g++) {
                    O[g][nb] = mfma16(pf0[g], vf0, O[g][nb]);
                    O[g][nb] = mfma16(pf1[g], vf1, O[g][nb]);
                }
            }
        }
        __builtin_amdgcn_s_setprio(0);

        // --- exp(i): eg = exp(s/8 + c*d) -> Ps (single-buffered; PV-read ->
        // exp-write are same-wave DS ops, retired in order) ---
        #pragma unroll
        for (int g = 0; g < 2; g++)
            #pragma unroll
            for (int c = 0; c < 4; c++) {
                const float e0 = __expf(fmaf(s4[g][c][0], 0.125f, cg * (float)gcur[g][c][0]));
                const float e1 = __expf(fmaf(s4[g][c][1], 0.125f, cg * (float)gcur[g][c][1]));
                const float e2 = __expf(fmaf(s4[g][c][2], 0.125f, cg * (float)gcur[g][c][2]));
                const float e3 = __expf(fmaf(s4[g][c][3], 0.125f, cg * (float)gcur[g][c][3]));
                G[g] += (e0 + e1) + (e2 + e3);
                bf16x4 pk;
                pk[0] = (__bf16)e0; pk[1] = (__bf16)e1;
                pk[2] = (__bf16)e2; pk[3] = (__bf16)e3;
                *(bf16x4*)&Ps[w][(g * 16 + lrow) * 72 + c * 16 + quad * 4] = pk;
            }
    }

    // --- final PV(NT-1) ---
    {
        const int prv = (NT - 1) & 1;
        bf16x8 pf0[2], pf1[2];
        #pragma unroll
        for (int g = 0; g < 2; g++) {
            pf0[g] = *(const bf16x8*)&Ps[w][(g * 16 + lrow) * 72 + quad * 8];
            pf1[g] = *(const bf16x8*)&Ps[w][(g * 16 + lrow) * 72 + 32 + quad * 8];
        }
        #pragma unroll
        for (int nb = 0; nb < 4; nb++) {
            bf16x8 vf0 = *(const bf16x8*)&Vt[prv][(nb * 16 + lrow) * 72 + quad * 8];
            bf16x8 vf1 = *(const bf16x8*)&Vt[prv][(nb * 16 + lrow) * 72 + 32 + quad * 8];
            #pragma unroll
            for (int g = 0; g < 2; g++) {
                O[g][nb] = mfma16(pf0[g], vf0, O[g][nb]);
                O[g][nb] = mfma16(pf1[g], vf1, O[g][nb]);
            }
        }
    }

    // Partial G per group: reduce across quads; raw f32 partials out.
    #pragma unroll
    for (int g = 0; g < 2; g++) {
        G[g] += __shfl_xor(G[g], 16);
        G[g] += __shfl_xor(G[g], 32);
    }

    #pragma unroll
    for (int g = 0; g < 2; g++) {
        float* Op = Opart + (size_t)z * (B_ * NQ_ * 1024)
                          + ((size_t)b * NQ_ + q0 + g * 16) * 1024 + h * HD_;
        #pragma unroll
        for (int r = 0; r < 4; r++) {
            const int qr = quad * 4 + r;
            #pragma unroll
            for (int nb = 0; nb < 4; nb++)
                Op[(size_t)qr * 1024 + nb * 16 + lrow] = O[g][nb][r];
        }
        if (lane < 16)
            Gpart[(size_t)z * (32 * 1024) + bh * 1024 + q0 + g * 16 + lane] = G[g];
    }
}

// Combine the two k-half partials: attnout = (O0+O1) * kpm_q / (G0+G1).
// 2048 x 1024 elements, 4 cols/thread -> 2048 blocks. ~21 MB traffic.
__global__ __launch_bounds__(256) void combine_kernel(
    const float* __restrict__ Opart, const float* __restrict__ Gpart,
    const int* __restrict__ kpmq, __bf16* __restrict__ attnout)
{
    const int idx = blockIdx.x * 256 + threadIdx.x;   // 0..524287
    const int m   = idx >> 8;            // row 0..2047
    const int c4  = (idx & 255) * 4;     // col 0..1020
    const int b   = m >> 10, q = m & 1023;
    const int h   = c4 >> 6;
    const float g = Gpart[(b * 16 + h) * 1024 + q]
                  + Gpart[32 * 1024 + (b * 16 + h) * 1024 + q];
    const float f = kpmq[b * NQ_ + q] ? 1.f / (g + 1e-30f) : 0.f;
    const float4 o0 = *(const float4*)(Opart + (size_t)m * 1024 + c4);
    const float4 o1 = *(const float4*)(Opart + (size_t)(B_ * NQ_) * 1024
                                              + (size_t)m * 1024 + c4);
    bf16x4 r;
    r[0] = (__bf16)((o0.x + o1.x) * f);
    r[1] = (__bf16)((o0.y + o1.y) * f);
    r[2] = (__bf16)((o0.z + o1.z) * f);
    r[3] = (__bf16)((o0.w + o1.w) * f);
    *(bf16x4*)&attnout[(size_t)m * 1024 + c4] = r;
}

// ---------------------------------------------------------------------------
extern "C" void kernel_launch(void* const* d_in, const int* in_sizes, int n_in,
                              void* d_out, int out_size, void* d_ws,
                              size_t ws_size, hipStream_t stream)
{
    const float* q      = (const float*)d_in[0];
    const float* k      = (const float*)d_in[1];
    const float* v      = (const float*)d_in[2];
    const float* dist   = (const float*)d_in[3];
    const int*   amask  = (const int*)d_in[4];
    const int*   kpmq   = (const int*)d_in[5];
    const int*   kpmk   = (const int*)d_in[6];
    const float* Wq     = (const float*)d_in[7];
    const float* Wk     = (const float*)d_in[8];
    const float* Wv     = (const float*)d_in[9];
    const float* Wo     = (const float*)d_in[10];
    const float* galpha = (const float*)d_in[11];

    char* p = (char*)d_ws;
    float*  msum = (float*)p;                 p += 256;
    __bf16* qb   = (__bf16*)p;                p += (size_t)2097152 * 2;
    __bf16* kb   = (__bf16*)p;                p += (size_t)4194304 * 2;
    __bf16* vb   = (__bf16*)p;                p += (size_t)4194304 * 2;
    __bf16* wqb  = (__bf16*)p;                p += (size_t)1048576 * 2;
    __bf16* wkb  = (__bf16*)p;                p += (size_t)1048576 * 2;
    __bf16* wvb  = (__bf16*)p;                p += (size_t)1048576 * 2;
    __bf16* wob  = (__bf16*)p;                p += (size_t)1048576 * 2;
    __bf16* qp   = (__bf16*)p;                p += (size_t)2097152 * 2;
    __bf16* kpb  = (__bf16*)p;                p += (size_t)4194304 * 2;
    __bf16* vpT  = (__bf16*)p;                p += (size_t)32 * 64 * VPAD * 2;
    __bf16* dmask = (__bf16*)p;               p += (size_t)2048 * GPAD * 2;
    __bf16* attnout = (__bf16*)p;             p += (size_t)2097152 * 2;

    // Split-K partial buffers OVERLAY the bf16 staging buffers, which are
    // dead after proj_dm_kernel: Opart (16 MiB) on kb+vb, Gpart on qb.
    float* Opart = (float*)kb;
    float* Gpart = (float*)qb;

    CvtArgs ca;
    ca.src[0] = q;  ca.src[1] = k;  ca.src[2] = v;
    ca.src[3] = Wq; ca.src[4] = Wk; ca.src[5] = Wv; ca.src[6] = Wo;
    ca.dst[0] = qb;  ca.dst[1] = kb;  ca.dst[2] = vb;
    ca.dst[3] = wqb; ca.dst[4] = wkb; ca.dst[5] = wvb; ca.dst[6] = wob;

    hipMemsetAsync(msum, 0, 256, stream);
    cvt_kernel<<<1792, 256, 0, stream>>>(ca);
    proj_dm_kernel<<<1792, 256, 0, stream>>>(qb, kb, vb, wqb, wkb, wvb,
                                             qp, kpb, vpT,
                                             dist, amask, kpmk, msum, dmask);
    attn_kernel<<<512, 256, 0, stream>>>(qp, kpb, vpT, dmask,
                                         msum, galpha, Opart, Gpart);
    combine_kernel<<<2048, 256, 0, stream>>>(Opart, Gpart, kpmq, attnout);
    oproj_kernel<<<dim3(64, 8), 256, 0, stream>>>(attnout, wob, (float*)d_out);
}